// Round 10
// baseline (277.051 us; speedup 1.0000x reference)
//
#include <hip/hip_runtime.h>
#include <hip/hip_bf16.h>
#include <stdint.h>

typedef __bf16 bf16x8 __attribute__((ext_vector_type(8)));
typedef __bf16 bf16x4 __attribute__((ext_vector_type(4)));
typedef float  f32x4  __attribute__((ext_vector_type(4)));

#define MFMA16(a, b, c) __builtin_amdgcn_mfma_f32_16x16x32_bf16((a), (b), (c), 0, 0, 0)

constexpr int BATCH = 4;
constexpr int TSEQ  = 2048;
constexpr int CDIM  = 1024;
constexpr int NHEAD = 16;
constexpr int HSZ   = 64;
constexpr size_t HEADELEMS = (size_t)BATCH * NHEAD * TSEQ * HSZ;  // 8388608

constexpr int LDF = 72;  // flash LDS stride (144 B)

// direct global->LDS DMA, 16 B per lane; LDS dest = wave-uniform base + lane*16
__device__ __forceinline__ void load_lds_128(const __bf16* g, __bf16* l) {
    __builtin_amdgcn_global_load_lds(
        (const __attribute__((address_space(1))) unsigned int*)g,
        (__attribute__((address_space(3))) unsigned int*)l,
        16, 0, 0);
}

// ---------------------------------------------------------------------------
// fp32 -> bf16 bulk convert (n multiple of 2048)
// ---------------------------------------------------------------------------
__global__ void conv_f32_bf16(const float* __restrict__ src, __bf16* __restrict__ dst, int n)
{
    const int i0 = (blockIdx.x * 256 + threadIdx.x) * 8;
    if (i0 >= n) return;
    float4 a = *(const float4*)(src + i0);
    float4 b = *(const float4*)(src + i0 + 4);
    bf16x8 o;
    o[0] = (__bf16)a.x; o[1] = (__bf16)a.y; o[2] = (__bf16)a.z; o[3] = (__bf16)a.w;
    o[4] = (__bf16)b.x; o[5] = (__bf16)b.y; o[6] = (__bf16)b.z; o[7] = (__bf16)b.w;
    *(bf16x8*)(dst + i0) = o;
}

// ---------------------------------------------------------------------------
// fp32 [K][N] -> bf16 transposed [N][K]. 32x32 LDS tiles, both sides coalesced.
// ---------------------------------------------------------------------------
__global__ void conv_transpose_bf16(const float* __restrict__ src, __bf16* __restrict__ dst,
                                    int K, int N)
{
    __shared__ __bf16 tile[32][33];
    const int n0 = blockIdx.x * 32, k0 = blockIdx.y * 32;
    const int tx = threadIdx.x & 31, ty = threadIdx.x >> 5;   // 32 x 8
    #pragma unroll
    for (int i = 0; i < 32; i += 8)
        tile[ty + i][tx] = (__bf16)src[(size_t)(k0 + ty + i) * N + n0 + tx];  // tile[k][n]
    __syncthreads();
    #pragma unroll
    for (int i = 0; i < 32; i += 8)
        dst[(size_t)(n0 + ty + i) * K + k0 + tx] = tile[tx][ty + i];          // dst[n][k]
}

// ---------------------------------------------------------------------------
// GEMM (m97 structure, ROUND-7 VERSION): C[M,N] = A[M,K]*BT[N,K]^T + bias.
// 128x128 tile, BK=32, single unpadded LDS buffer, global_load_lds width-16,
// two barriers per K-step with COMPILER-managed waitcnt (verified race-free
// r6-r7). NOTE (r8/r9 post-mortem): explicit dbuf + hand vmcnt(0) regressed
// 99->120 us — m99/m100/m131-141 reproduced. Do not re-add.
// EPI=0: scatter q[b,h,t,d], k[b,h,t,d], v transposed [b,h,d,t] (bf16).
// EPI=1: row-major fp32 store.
// ---------------------------------------------------------------------------
template<int EPI>
__global__ __launch_bounds__(256, 2)
void gemm_bt(const __bf16* __restrict__ A, const __bf16* __restrict__ BT,
             const float* __restrict__ bias, void* __restrict__ outv,
             int M, int N, int K)
{
    __shared__ __bf16 As[128 * 32];   // [row][k], unpadded (global_load_lds layout)
    __shared__ __bf16 Bs[128 * 32];   // [n][k],   unpadded

    const int t    = threadIdx.x;
    const int wave = t >> 6, lane = t & 63;
    const int quad = lane >> 4, l16 = lane & 15;
    const int bm = blockIdx.y * 128, bn = blockIdx.x * 128;
    const int wm = (wave >> 1) * 64, wn = (wave & 1) * 64;

    const int lrow = lane >> 2, lchunk = lane & 3;

    f32x4 acc[4][4];
    #pragma unroll
    for (int i = 0; i < 4; ++i)
        #pragma unroll
        for (int j = 0; j < 4; ++j)
            acc[i][j] = (f32x4){0.f, 0.f, 0.f, 0.f};

    const int c0 = wave * 2, c1 = wave * 2 + 1;
    const __bf16* a0 = A  + (size_t)(bm + 16 * c0 + lrow) * K + 8 * lchunk;
    const __bf16* a1 = A  + (size_t)(bm + 16 * c1 + lrow) * K + 8 * lchunk;
    const __bf16* b0 = BT + (size_t)(bn + 16 * c0 + lrow) * K + 8 * lchunk;
    const __bf16* b1 = BT + (size_t)(bn + 16 * c1 + lrow) * K + 8 * lchunk;

    for (int k0 = 0; k0 < K; k0 += 32) {
        load_lds_128(a0 + k0, &As[c0 * 512]);
        load_lds_128(a1 + k0, &As[c1 * 512]);
        load_lds_128(b0 + k0, &Bs[c0 * 512]);
        load_lds_128(b1 + k0, &Bs[c1 * 512]);
        __syncthreads();

        bf16x8 af[4], bfr[4];
        #pragma unroll
        for (int i = 0; i < 4; ++i)
            af[i]  = *(const bf16x8*)(&As[(wm + i * 16 + l16) * 32 + quad * 8]);
        #pragma unroll
        for (int i = 0; i < 4; ++i)
            bfr[i] = *(const bf16x8*)(&Bs[(wn + i * 16 + l16) * 32 + quad * 8]);
        #pragma unroll
        for (int mi = 0; mi < 4; ++mi)
            #pragma unroll
            for (int ni = 0; ni < 4; ++ni)
                acc[mi][ni] = MFMA16(af[mi], bfr[ni], acc[mi][ni]);
        __syncthreads();
    }

    if constexpr (EPI == 0) {
        __bf16* outp = (__bf16*)outv;
        #pragma unroll
        for (int ni = 0; ni < 4; ++ni) {
            const int col = bn + wn + ni * 16 + l16;          // 0..3071
            const float bv = bias[col];
            const int which = col >> 10;                      // 0=q 1=k 2=v
            const int c = col & 1023;
            const int h = c >> 6, d = c & 63;
            #pragma unroll
            for (int mi = 0; mi < 4; ++mi)
                #pragma unroll
                for (int r = 0; r < 4; ++r) {
                    const int row = bm + wm + mi * 16 + quad * 4 + r;  // 0..8191
                    const int bb = row >> 11, tt = row & 2047;
                    size_t idx;
                    if (which == 2)  // v transposed: [b,h,d,t]
                        idx = 2 * HEADELEMS + ((((size_t)bb * NHEAD + h) * HSZ + d) * TSEQ + tt);
                    else
                        idx = (size_t)which * HEADELEMS
                            + ((((size_t)bb * NHEAD + h) * TSEQ + tt) * HSZ + d);
                    outp[idx] = (__bf16)(acc[mi][ni][r] + bv);
                }
        }
    } else {
        float* outp = (float*)outv;
        #pragma unroll
        for (int ni = 0; ni < 4; ++ni) {
            const int col = bn + wn + ni * 16 + l16;
            const float bv = bias[col];
            #pragma unroll
            for (int mi = 0; mi < 4; ++mi)
                #pragma unroll
                for (int r = 0; r < 4; ++r) {
                    const int row = bm + wm + mi * 16 + quad * 4 + r;
                    outp[(size_t)row * N + col] = acc[mi][ni][r] + bv;
                }
        }
    }
}

// ---------------------------------------------------------------------------
// Flash attention (causal), UNNORMALIZED, S^T formulation (see round-7 notes).
// Q,K: [B*NH, T, 64]; V: [B*NH, 64, T] (transposed). Y: [B,T,C] bf16.
// ---------------------------------------------------------------------------
__global__ __launch_bounds__(256, 4)
void flash_attn(const __bf16* __restrict__ Q, const __bf16* __restrict__ Kg,
                const __bf16* __restrict__ Vg, __bf16* __restrict__ Y)
{
    __shared__ __bf16 Ks[64 * LDF];      // [key][d]
    __shared__ __bf16 Vs[64 * LDF];      // [d][key]
    __shared__ __bf16 Ps[4][32 * LDF];   // per-wave [q][key] (wave-private)

    const int t = threadIdx.x, wave = t >> 6, lane = t & 63;
    const int quad = lane >> 4, l16 = lane & 15;
    const int bh = blockIdx.x;
    const int q0 = ((int)gridDim.y - 1 - (int)blockIdx.y) * 128;  // longest first
    const size_t base = (size_t)bh * TSEQ * HSZ;

    const float sc = 0.125f * 1.44269504088896341f;  // log2(e)/sqrt(HS)

    // Q fragments (B-operand: n=l16 -> q row), pre-scaled by sc
    bf16x8 qf[2][2];
    #pragma unroll
    for (int mi = 0; mi < 2; ++mi) {
        const int qrow = q0 + wave * 32 + mi * 16 + l16;
        #pragma unroll
        for (int h = 0; h < 2; ++h) {
            bf16x8 raw = *(const bf16x8*)(Q + base + (size_t)qrow * HSZ + h * 32 + quad * 8);
            #pragma unroll
            for (int j = 0; j < 8; ++j) qf[mi][h][j] = (__bf16)((float)raw[j] * sc);
        }
    }

    bf16x8 ones;
    #pragma unroll
    for (int j = 0; j < 8; ++j) ones[j] = (__bf16)1.0f;

    f32x4 oacc[2][4];   // [mi][dt], C-layout row=q(quad*4+r), col=d(l16)
    f32x4 lacc[2];      // [mi],     row=q(quad*4+r), all cols equal
    #pragma unroll
    for (int mi = 0; mi < 2; ++mi) {
        lacc[mi] = (f32x4){0.f, 0.f, 0.f, 0.f};
        #pragma unroll
        for (int dt = 0; dt < 4; ++dt) oacc[mi][dt] = (f32x4){0.f, 0.f, 0.f, 0.f};
    }

    const int s_row = t >> 2, s_c16 = (t & 3) * 16;

    const int iters = q0 / 64 + 2;
    for (int it = 0; it < iters; ++it) {
        const int kt = it * 64;
        {   // stage K [key][d]
            const __bf16* kp = Kg + base + (size_t)(kt + s_row) * HSZ + s_c16;
            bf16x8 v0 = *(const bf16x8*)kp;
            bf16x8 v1 = *(const bf16x8*)(kp + 8);
            *(bf16x8*)(&Ks[s_row * LDF + s_c16])     = v0;
            *(bf16x8*)(&Ks[s_row * LDF + s_c16 + 8]) = v1;
        }
        {   // stage V [d][key]
            const __bf16* vp = Vg + base + (size_t)s_row * TSEQ + kt + s_c16;
            bf16x8 v0 = *(const bf16x8*)vp;
            bf16x8 v1 = *(const bf16x8*)(vp + 8);
            *(bf16x8*)(&Vs[s_row * LDF + s_c16])     = v0;
            *(bf16x8*)(&Vs[s_row * LDF + s_c16 + 8]) = v1;
        }
        __syncthreads();

        const bool active = (kt <= q0 + wave * 32 + 31);
        if (active) {
            // ---- S^T = K·Q^T : [4 key-tiles][2 q-tiles], C row=key, col=q ----
            f32x4 st[4][2];
            #pragma unroll
            for (int ktl = 0; ktl < 4; ++ktl) {
                bf16x8 kf0 = *(const bf16x8*)(&Ks[(ktl * 16 + l16) * LDF + quad * 8]);
                bf16x8 kf1 = *(const bf16x8*)(&Ks[(ktl * 16 + l16) * LDF + 32 + quad * 8]);
                #pragma unroll
                for (int mi = 0; mi < 2; ++mi) {
                    f32x4 a = (f32x4){0.f, 0.f, 0.f, 0.f};
                    a = MFMA16(kf0, qf[mi][0], a);
                    a = MFMA16(kf1, qf[mi][1], a);
                    st[ktl][mi] = a;
                }
            }

            // ---- causal mask (near diagonal only) ----
            if (kt + 63 >= q0 + wave * 32) {
                #pragma unroll
                for (int ktl = 0; ktl < 4; ++ktl)
                    #pragma unroll
                    for (int mi = 0; mi < 2; ++mi)
                        #pragma unroll
                        for (int r = 0; r < 4; ++r) {
                            const int key = kt + ktl * 16 + quad * 4 + r;
                            const int qr  = q0 + wave * 32 + mi * 16 + l16;
                            if (key > qr) st[ktl][mi][r] = -1e30f;
                        }
            }

            // ---- P = exp2(S^T), packed b64 writes into Ps[q][key] ----
            #pragma unroll
            for (int ktl = 0; ktl < 4; ++ktl)
                #pragma unroll
                for (int mi = 0; mi < 2; ++mi) {
                    bf16x4 pv;
                    #pragma unroll
                    for (int r = 0; r < 4; ++r)
                        pv[r] = (__bf16)exp2f(st[ktl][mi][r]);
                    *(bf16x4*)(&Ps[wave][(mi * 16 + l16) * LDF + ktl * 16 + quad * 4]) = pv;
                }

            // wave-local fence: DS writes complete before reload (wave-private Ps)
            asm volatile("s_waitcnt lgkmcnt(0)" ::: "memory");

            // ---- O += P·V^T, l += P·1 ----
            bf16x8 pf[2][2];
            #pragma unroll
            for (int mi = 0; mi < 2; ++mi) {
                pf[mi][0] = *(const bf16x8*)(&Ps[wave][(mi * 16 + l16) * LDF + quad * 8]);
                pf[mi][1] = *(const bf16x8*)(&Ps[wave][(mi * 16 + l16) * LDF + 32 + quad * 8]);
                lacc[mi] = MFMA16(pf[mi][0], ones, lacc[mi]);
                lacc[mi] = MFMA16(pf[mi][1], ones, lacc[mi]);
            }
            #pragma unroll
            for (int dt = 0; dt < 4; ++dt) {
                bf16x8 vf0 = *(const bf16x8*)(&Vs[(dt * 16 + l16) * LDF + quad * 8]);
                bf16x8 vf1 = *(const bf16x8*)(&Vs[(dt * 16 + l16) * LDF + 32 + quad * 8]);
                #pragma unroll
                for (int mi = 0; mi < 2; ++mi) {
                    oacc[mi][dt] = MFMA16(pf[mi][0], vf0, oacc[mi][dt]);
                    oacc[mi][dt] = MFMA16(pf[mi][1], vf1, oacc[mi][dt]);
                }
            }
        }
        __syncthreads();
    }

    // ---- epilogue: y = O / l (both C-layout, no cross-lane moves) ----
    const int b = bh >> 4, h = bh & 15;
    #pragma unroll
    for (int mi = 0; mi < 2; ++mi) {
        const f32x4 linv = {1.f / lacc[mi][0], 1.f / lacc[mi][1],
                            1.f / lacc[mi][2], 1.f / lacc[mi][3]};
        #pragma unroll
        for (int dt = 0; dt < 4; ++dt)
            #pragma unroll
            for (int r = 0; r < 4; ++r) {
                const int tt = q0 + wave * 32 + mi * 16 + quad * 4 + r;
                const int d  = dt * 16 + l16;
                Y[((size_t)(b * TSEQ + tt) * CDIM) + h * HSZ + d] =
                    (__bf16)(oacc[mi][dt][r] * linv[r]);
            }
    }
}

// ---------------------------------------------------------------------------
extern "C" void kernel_launch(void* const* d_in, const int* in_sizes, int n_in,
                              void* d_out, int out_size, void* d_ws, size_t ws_size,
                              hipStream_t stream)
{
    const int NX = 8388608, NWA = 3145728, NWP = 1048576;
    char* wsb = (char*)d_ws;

    size_t off = 0;
    __bf16* cx   = (__bf16*)(wsb + off); off += (size_t)2 * NX;
    __bf16* cwaT = (__bf16*)(wsb + off); off += (size_t)2 * NWA;   // [3072][1024]
    __bf16* cwpT = (__bf16*)(wsb + off); off += (size_t)2 * NWP;   // [1024][1024]
    __bf16* q    = (__bf16*)(wsb + off);
    __bf16* y    = q + 3 * HEADELEMS;

    const float* xf = (const float*)d_in[0];
    const float* ba = (const float*)d_in[2];
    const float* bp = (const float*)d_in[4];

    conv_f32_bf16<<<NX / 2048, 256, 0, stream>>>(xf, cx, NX);
    conv_transpose_bf16<<<dim3(3 * CDIM / 32, CDIM / 32), 256, 0, stream>>>(
        (const float*)d_in[1], cwaT, CDIM, 3 * CDIM);
    conv_transpose_bf16<<<dim3(CDIM / 32, CDIM / 32), 256, 0, stream>>>(
        (const float*)d_in[3], cwpT, CDIM, CDIM);

    // qkv = x @ W_attn + b_attn -> q/k [b,h,t,d], v [b,h,d,t]
    gemm_bt<0><<<dim3(3 * CDIM / 128, BATCH * TSEQ / 128), 256, 0, stream>>>(
        cx, cwaT, ba, q, BATCH * TSEQ, 3 * CDIM, CDIM);

    // causal flash attention -> y [B,T,C] bf16
    flash_attn<<<dim3(BATCH * NHEAD, TSEQ / 128), 256, 0, stream>>>(
        q, q + HEADELEMS, q + 2 * HEADELEMS, y);

    // out = y @ W_proj + b_proj (fp32 out)
    gemm_bt<1><<<dim3(CDIM / 128, BATCH * TSEQ / 128), 256, 0, stream>>>(
        y, cwpT, bp, d_out, BATCH * TSEQ, CDIM, CDIM);
}